// Round 2
// baseline (65.670 us; speedup 1.0000x reference)
//
#include <hip/hip_runtime.h>
#include <math.h>

#define BINS 10
#define NCLS 1000
#define NC4  250   // 1000 floats = 250 float4 per row
#define EPSV 1e-8f

// One 64-lane wave per row. Each lane loads up to 4 float4 (coalesced, row
// stride 4000 B, 16B-aligned). Logits are N(0,1) so sum(exp(x)) is computed
// directly (no max subtraction) — matches the reference log(sum(exp)+eps)
// formula exactly and removes one butterfly reduction from the serial path.
// pred[row, target] is extracted from registers via uniform-select + shfl
// (no dependent global load). Per-bin (count, loss-sum) accumulate in LDS;
// each block flushes <=10 global atomics.
__global__ __launch_bounds__(256, 8) void ghmc_pass1(
    const float* __restrict__ pred,
    const int*   __restrict__ target,
    int*   __restrict__ gcnt,
    float* __restrict__ gsum,
    int rows_per_block, int nrows)
{
    __shared__ int   s_cnt[BINS];
    __shared__ float s_sum[BINS];
    if (threadIdx.x < BINS) { s_cnt[threadIdx.x] = 0; s_sum[threadIdx.x] = 0.0f; }
    __syncthreads();

    const int lane = threadIdx.x & 63;
    const int wave = threadIdx.x >> 6;
    const int base = blockIdx.x * rows_per_block;

    for (int r = wave; r < rows_per_block; r += 4) {
        const int row = base + r;
        if (row >= nrows) break;
        const float4* rp = (const float4*)(pred + (size_t)row * NCLS);

        // 250 float4: chunks at lane, lane+64, lane+128 always valid
        // (max idx 191 < 250); chunk 3 valid only for lane < 58.
        float4 v0 = rp[lane];
        float4 v1 = rp[lane + 64];
        float4 v2 = rp[lane + 128];
        float4 v3;
        if (lane + 192 < NC4) {
            v3 = rp[lane + 192];
        } else {
            v3.x = -INFINITY; v3.y = -INFINITY; v3.z = -INFINITY; v3.w = -INFINITY;
        }
        const int t = target[row];   // same addr across wave -> broadcast load

        // exp(-inf) = 0, so masked chunk-3 lanes contribute nothing.
        float s = __expf(v0.x) + __expf(v0.y) + __expf(v0.z) + __expf(v0.w)
                + __expf(v1.x) + __expf(v1.y) + __expf(v1.z) + __expf(v1.w)
                + __expf(v2.x) + __expf(v2.y) + __expf(v2.z) + __expf(v2.w)
                + __expf(v3.x) + __expf(v3.y) + __expf(v3.z) + __expf(v3.w);
        #pragma unroll
        for (int off = 32; off >= 1; off >>= 1)
            s += __shfl_xor(s, off);

        // pred[row, t] is already in registers: float4 index f = t>>2 lives in
        // chunk c = f>>6 at lane f&63, component t&3. c and comp are
        // wave-uniform (t is broadcast), so the selects don't diverge.
        const int f = t >> 2, comp = t & 3, src = f & 63, c = f >> 6;
        const float4 vc = (c == 0) ? v0 : (c == 1) ? v1 : (c == 2) ? v2 : v3;
        const float sel = (comp == 0) ? vc.x : (comp == 1) ? vc.y
                        : (comp == 2) ? vc.z : vc.w;
        const float pt = __shfl(sel, src);

        if (lane == 0) {
            const float loss = -pt + __logf(s + EPSV);  // -pred[t] + log(sum exp + eps)
            const float p = __expf(pt) / s;             // softmax[i, t]
            const float g = 1.0f - p;
            int b = (int)floorf(g * 10.0f);
            b = min(max(b, 0), BINS - 1);
            atomicAdd(&s_cnt[b], 1);
            atomicAdd(&s_sum[b], loss);
        }
    }

    __syncthreads();
    if (threadIdx.x < BINS && s_cnt[threadIdx.x] > 0) {
        atomicAdd(&gcnt[threadIdx.x], s_cnt[threadIdx.x]);
        atomicAdd(&gsum[threadIdx.x], s_sum[threadIdx.x]);
    }
}

// Pass 2: combine the 10 bins.
// out = sum_b (loss_sum[b] / counts[b]) / n_nonempty
__global__ void ghmc_pass2(const int* __restrict__ gcnt,
                           const float* __restrict__ gsum,
                           float* __restrict__ out)
{
    if (threadIdx.x == 0 && blockIdx.x == 0) {
        int n = 0;
        float acc = 0.0f;
        for (int b = 0; b < BINS; ++b) {
            if (gcnt[b] > 0) {
                n += 1;
                acc += gsum[b] / (float)gcnt[b];
            }
        }
        out[0] = acc / (float)max(n, 1);
    }
}

extern "C" void kernel_launch(void* const* d_in, const int* in_sizes, int n_in,
                              void* d_out, int out_size, void* d_ws, size_t ws_size,
                              hipStream_t stream)
{
    const float* pred   = (const float*)d_in[0];
    const int*   target = (const int*)d_in[1];
    const int nrows = in_sizes[1];          // 65536

    int*   gcnt = (int*)d_ws;
    float* gsum = (float*)((char*)d_ws + 64);

    // ws is poisoned 0xAA and not re-poisoned between replays: zero it every call.
    hipMemsetAsync(d_ws, 0, 128, stream);

    const int rows_per_block = 32;          // 2048 blocks -> 8 blocks/CU
    const int blocks = (nrows + rows_per_block - 1) / rows_per_block;
    ghmc_pass1<<<blocks, 256, 0, stream>>>(pred, target, gcnt, gsum,
                                           rows_per_block, nrows);
    ghmc_pass2<<<1, 64, 0, stream>>>(gcnt, gsum, (float*)d_out);
}

// Round 3
// 57.969 us; speedup vs baseline: 1.1329x; 1.1329x over previous
//
#include <hip/hip_runtime.h>
#include <math.h>

#define BINS 10
#define NCLS 1000
#define NC4  250   // 1000 floats = 250 float4 per row
#define EPSV 1e-8f

// One 64-lane wave per row, 2 rows per iteration (8 independent 1KB loads in
// flight -> memory-level parallelism; R1's 4-load version ran at 4.5/6.3 TB/s,
// latency-limited). Logits are N(0,1) so sum(exp(x)) is computed directly (no
// max pass) — matches the reference log(sum(exp)+eps) formula exactly.
// pred[row,target] is loaded by all lanes at the same address (broadcast,
// L1-hot) and issued BEFORE the exp work so its latency hides. Per-bin
// (count, loss-sum) accumulate in LDS; each block flushes <=10 global atomics.
__global__ __launch_bounds__(256) void ghmc_pass1(
    const float* __restrict__ pred,
    const int*   __restrict__ target,
    int*   __restrict__ gcnt,
    float* __restrict__ gsum,
    int rows_per_block, int nrows)
{
    __shared__ int   s_cnt[BINS];
    __shared__ float s_sum[BINS];
    if (threadIdx.x < BINS) { s_cnt[threadIdx.x] = 0; s_sum[threadIdx.x] = 0.0f; }
    __syncthreads();

    const int lane = threadIdx.x & 63;
    const int wave = threadIdx.x >> 6;
    const int base = blockIdx.x * rows_per_block;

    // Each wave owns rows {base + wave*2 + k*8 + {0,1}}.
    for (int r = wave * 2; r < rows_per_block; r += 8) {
        const int rowA = base + r;
        if (rowA >= nrows) break;
        const int rowB_raw = rowA + 1;
        const bool haveB = rowB_raw < nrows;
        const int rowB = haveB ? rowB_raw : rowA;   // clamp: loads stay valid

        const float4* rpA = (const float4*)(pred + (size_t)rowA * NCLS);
        const float4* rpB = (const float4*)(pred + (size_t)rowB * NCLS);

        // 250 float4/row: chunks 0..2 always valid (max idx 191), chunk 3
        // valid only for lane < 58.
        float4 a0 = rpA[lane];
        float4 a1 = rpA[lane + 64];
        float4 a2 = rpA[lane + 128];
        float4 b0 = rpB[lane];
        float4 b1 = rpB[lane + 64];
        float4 b2 = rpB[lane + 128];
        float4 a3, b3;
        if (lane + 192 < NC4) {
            a3 = rpA[lane + 192];
            b3 = rpB[lane + 192];
        } else {
            a3.x = a3.y = a3.z = a3.w = -INFINITY;
            b3.x = b3.y = b3.z = b3.w = -INFINITY;
        }

        // Broadcast loads (same addr wave-wide). Issue early: latency hides
        // under the 32 exps below.
        const int tA = target[rowA];
        const int tB = target[rowB];
        const float ptA = pred[(size_t)rowA * NCLS + tA];
        const float ptB = pred[(size_t)rowB * NCLS + tB];

        // exp(-inf) = 0, so masked chunk-3 lanes contribute nothing.
        float sA = __expf(a0.x) + __expf(a0.y) + __expf(a0.z) + __expf(a0.w)
                 + __expf(a1.x) + __expf(a1.y) + __expf(a1.z) + __expf(a1.w)
                 + __expf(a2.x) + __expf(a2.y) + __expf(a2.z) + __expf(a2.w)
                 + __expf(a3.x) + __expf(a3.y) + __expf(a3.z) + __expf(a3.w);
        float sB = __expf(b0.x) + __expf(b0.y) + __expf(b0.z) + __expf(b0.w)
                 + __expf(b1.x) + __expf(b1.y) + __expf(b1.z) + __expf(b1.w)
                 + __expf(b2.x) + __expf(b2.y) + __expf(b2.z) + __expf(b2.w)
                 + __expf(b3.x) + __expf(b3.y) + __expf(b3.z) + __expf(b3.w);
        #pragma unroll
        for (int off = 32; off >= 1; off >>= 1) {
            sA += __shfl_xor(sA, off);
            sB += __shfl_xor(sB, off);
        }

        if (lane == 0) {
            {
                const float loss = -ptA + __logf(sA + EPSV);
                const float g = 1.0f - __expf(ptA) / sA;
                int b = (int)floorf(g * 10.0f);
                b = min(max(b, 0), BINS - 1);
                atomicAdd(&s_cnt[b], 1);
                atomicAdd(&s_sum[b], loss);
            }
            if (haveB) {
                const float loss = -ptB + __logf(sB + EPSV);
                const float g = 1.0f - __expf(ptB) / sB;
                int b = (int)floorf(g * 10.0f);
                b = min(max(b, 0), BINS - 1);
                atomicAdd(&s_cnt[b], 1);
                atomicAdd(&s_sum[b], loss);
            }
        }
    }

    __syncthreads();
    if (threadIdx.x < BINS && s_cnt[threadIdx.x] > 0) {
        atomicAdd(&gcnt[threadIdx.x], s_cnt[threadIdx.x]);
        atomicAdd(&gsum[threadIdx.x], s_sum[threadIdx.x]);
    }
}

// Pass 2: combine the 10 bins.
// out = sum_b (loss_sum[b] / counts[b]) / n_nonempty
__global__ void ghmc_pass2(const int* __restrict__ gcnt,
                           const float* __restrict__ gsum,
                           float* __restrict__ out)
{
    if (threadIdx.x == 0 && blockIdx.x == 0) {
        int n = 0;
        float acc = 0.0f;
        for (int b = 0; b < BINS; ++b) {
            if (gcnt[b] > 0) {
                n += 1;
                acc += gsum[b] / (float)gcnt[b];
            }
        }
        out[0] = acc / (float)max(n, 1);
    }
}

extern "C" void kernel_launch(void* const* d_in, const int* in_sizes, int n_in,
                              void* d_out, int out_size, void* d_ws, size_t ws_size,
                              hipStream_t stream)
{
    const float* pred   = (const float*)d_in[0];
    const int*   target = (const int*)d_in[1];
    const int nrows = in_sizes[1];          // 65536

    int*   gcnt = (int*)d_ws;
    float* gsum = (float*)((char*)d_ws + 64);

    // ws is poisoned 0xAA and not re-poisoned between replays: zero it every call.
    hipMemsetAsync(d_ws, 0, 128, stream);

    const int rows_per_block = 64;          // 1024 blocks, 4 waves, 16 rows/wave
    const int blocks = (nrows + rows_per_block - 1) / rows_per_block;
    ghmc_pass1<<<blocks, 256, 0, stream>>>(pred, target, gcnt, gsum,
                                           rows_per_block, nrows);
    ghmc_pass2<<<1, 64, 0, stream>>>(gcnt, gsum, (float*)d_out);
}

// Round 4
// 53.702 us; speedup vs baseline: 1.2229x; 1.0794x over previous
//
#include <hip/hip_runtime.h>
#include <math.h>

#define BINS 10
#define NCLS 1000
#define EPSV 1e-8f

// Full-wave (64-lane) sum via DPP: 6 dependent VALU adds (~50 cy) instead of
// 6 ds_bpermute (~720 cy). Valid total lands in lane 63.
__device__ __forceinline__ float dpp_reduce_add_lane63(float x) {
    int t;
    t = __builtin_amdgcn_update_dpp(0, __float_as_int(x), 0x111, 0xF, 0xF, true); x += __int_as_float(t); // row_shr:1
    t = __builtin_amdgcn_update_dpp(0, __float_as_int(x), 0x112, 0xF, 0xF, true); x += __int_as_float(t); // row_shr:2
    t = __builtin_amdgcn_update_dpp(0, __float_as_int(x), 0x114, 0xF, 0xF, true); x += __int_as_float(t); // row_shr:4
    t = __builtin_amdgcn_update_dpp(0, __float_as_int(x), 0x118, 0xF, 0xF, true); x += __int_as_float(t); // row_shr:8
    t = __builtin_amdgcn_update_dpp(0, __float_as_int(x), 0x142, 0xF, 0xF, true); x += __int_as_float(t); // row_bcast:15
    t = __builtin_amdgcn_update_dpp(0, __float_as_int(x), 0x143, 0xF, 0xF, true); x += __int_as_float(t); // row_bcast:31
    return x; // lane 63 holds the full 64-lane sum
}

// Tree-shaped sum of exp over 16 values (depth 4, not a 15-deep chain).
__device__ __forceinline__ float exp16_sum(const float4& v0, const float4& v1,
                                           const float4& v2, const float4& v3) {
    float a0 = __expf(v0.x) + __expf(v0.y), a1 = __expf(v0.z) + __expf(v0.w);
    float a2 = __expf(v1.x) + __expf(v1.y), a3 = __expf(v1.z) + __expf(v1.w);
    float a4 = __expf(v2.x) + __expf(v2.y), a5 = __expf(v2.z) + __expf(v2.w);
    float a6 = __expf(v3.x) + __expf(v3.y), a7 = __expf(v3.z) + __expf(v3.w);
    float b0 = a0 + a1, b1 = a2 + a3, b2 = a4 + a5, b3 = a6 + a7;
    return (b0 + b1) + (b2 + b3);
}

// One wave per row, 2 rows per pipeline stage, 2-deep software pipeline.
// 64 rows/block, 4 waves -> 16 rows/wave, 8 fully-unrolled stages.
// Targets preloaded (constant-indexed regs) so pred[row,t] broadcast loads
// issue one full stage ahead. Per-bin (count, loss-sum) in LDS; <=10 global
// atomics per block.
__global__ __launch_bounds__(256) void ghmc_pass1(
    const float* __restrict__ pred,
    const int*   __restrict__ target,
    int*   __restrict__ gcnt,
    float* __restrict__ gsum,
    int nrows)
{
    __shared__ int   s_cnt[BINS];
    __shared__ float s_sum[BINS];
    if (threadIdx.x < BINS) { s_cnt[threadIdx.x] = 0; s_sum[threadIdx.x] = 0.0f; }
    __syncthreads();

    const int lane = threadIdx.x & 63;
    const int wv   = threadIdx.x >> 6;
    const int base = blockIdx.x * 64;
    const float NEG = -INFINITY;

    // Preload all 16 targets (broadcast 4B loads, L2/L3-resident).
    int tgt[16];
    #pragma unroll
    for (int k = 0; k < 8; ++k) {
        const int rA = min(base + wv * 2 + k * 8, nrows - 1);
        tgt[2 * k]     = target[rA];
        tgt[2 * k + 1] = target[min(rA + 1, nrows - 1)];
    }

    float4 A0[2], A1[2], A2[2], A3[2], B0[2], B1[2], B2[2], B3[2];
    float  pA[2], pB[2];

#define LOADK(kk, pp) do {                                                    \
    const int rA_ = min(base + wv * 2 + (kk) * 8, nrows - 1);                 \
    const int rB_ = min(rA_ + 1, nrows - 1);                                  \
    const float4* rpA_ = (const float4*)(pred + (size_t)rA_ * NCLS);          \
    const float4* rpB_ = (const float4*)(pred + (size_t)rB_ * NCLS);          \
    A0[pp] = rpA_[lane]; A1[pp] = rpA_[lane + 64]; A2[pp] = rpA_[lane + 128]; \
    B0[pp] = rpB_[lane]; B1[pp] = rpB_[lane + 64]; B2[pp] = rpB_[lane + 128]; \
    if (lane < 58) { A3[pp] = rpA_[lane + 192]; B3[pp] = rpB_[lane + 192]; }  \
    else { A3[pp] = make_float4(NEG, NEG, NEG, NEG);                          \
           B3[pp] = make_float4(NEG, NEG, NEG, NEG); }                        \
    pA[pp] = pred[(size_t)rA_ * NCLS + tgt[2 * (kk)]];                        \
    pB[pp] = pred[(size_t)rB_ * NCLS + tgt[2 * (kk) + 1]];                    \
} while (0)

    LOADK(0, 0);  // prologue

    #pragma unroll
    for (int k = 0; k < 8; ++k) {
        const int p = k & 1, q = p ^ 1;
        if (k < 7) LOADK(k + 1, q);   // prefetch next stage (hides HBM latency)

        float sA = exp16_sum(A0[p], A1[p], A2[p], A3[p]);
        float sB = exp16_sum(B0[p], B1[p], B2[p], B3[p]);
        sA = dpp_reduce_add_lane63(sA);
        sB = dpp_reduce_add_lane63(sB);

        if (lane == 63) {
            const int rA = base + wv * 2 + k * 8;
            if (rA < nrows) {
                const float loss = -pA[p] + __logf(sA + EPSV);
                const float g = 1.0f - __expf(pA[p]) / sA;
                int b = (int)floorf(g * 10.0f);
                b = min(max(b, 0), BINS - 1);
                atomicAdd(&s_cnt[b], 1);
                atomicAdd(&s_sum[b], loss);
            }
            if (rA + 1 < nrows) {
                const float loss = -pB[p] + __logf(sB + EPSV);
                const float g = 1.0f - __expf(pB[p]) / sB;
                int b = (int)floorf(g * 10.0f);
                b = min(max(b, 0), BINS - 1);
                atomicAdd(&s_cnt[b], 1);
                atomicAdd(&s_sum[b], loss);
            }
        }
    }
#undef LOADK

    __syncthreads();
    if (threadIdx.x < BINS && s_cnt[threadIdx.x] > 0) {
        atomicAdd(&gcnt[threadIdx.x], s_cnt[threadIdx.x]);
        atomicAdd(&gsum[threadIdx.x], s_sum[threadIdx.x]);
    }
}

// Pass 2: combine the 10 bins.
// out = sum_b (loss_sum[b] / counts[b]) / n_nonempty
__global__ void ghmc_pass2(const int* __restrict__ gcnt,
                           const float* __restrict__ gsum,
                           float* __restrict__ out)
{
    if (threadIdx.x == 0 && blockIdx.x == 0) {
        int n = 0;
        float acc = 0.0f;
        for (int b = 0; b < BINS; ++b) {
            if (gcnt[b] > 0) {
                n += 1;
                acc += gsum[b] / (float)gcnt[b];
            }
        }
        out[0] = acc / (float)max(n, 1);
    }
}

extern "C" void kernel_launch(void* const* d_in, const int* in_sizes, int n_in,
                              void* d_out, int out_size, void* d_ws, size_t ws_size,
                              hipStream_t stream)
{
    const float* pred   = (const float*)d_in[0];
    const int*   target = (const int*)d_in[1];
    const int nrows = in_sizes[1];          // 65536

    int*   gcnt = (int*)d_ws;
    float* gsum = (float*)((char*)d_ws + 64);

    // ws is poisoned 0xAA and not re-poisoned between replays: zero it every call.
    hipMemsetAsync(d_ws, 0, 128, stream);

    const int blocks = (nrows + 63) / 64;   // 1024 blocks, 4 waves each
    ghmc_pass1<<<blocks, 256, 0, stream>>>(pred, target, gcnt, gsum, nrows);
    ghmc_pass2<<<1, 64, 0, stream>>>(gcnt, gsum, (float*)d_out);
}

// Round 5
// 50.505 us; speedup vs baseline: 1.3003x; 1.0633x over previous
//
#include <hip/hip_runtime.h>
#include <math.h>

#define BINS 10
#define NCLS 1000
#define EPSV 1e-8f

// Full-wave (64-lane) sum via DPP: 6 dependent VALU adds (~50 cy) instead of
// 6 ds_bpermute (~720 cy). Valid total lands in lane 63.
__device__ __forceinline__ float dpp_reduce_add_lane63(float x) {
    int t;
    t = __builtin_amdgcn_update_dpp(0, __float_as_int(x), 0x111, 0xF, 0xF, true); x += __int_as_float(t); // row_shr:1
    t = __builtin_amdgcn_update_dpp(0, __float_as_int(x), 0x112, 0xF, 0xF, true); x += __int_as_float(t); // row_shr:2
    t = __builtin_amdgcn_update_dpp(0, __float_as_int(x), 0x114, 0xF, 0xF, true); x += __int_as_float(t); // row_shr:4
    t = __builtin_amdgcn_update_dpp(0, __float_as_int(x), 0x118, 0xF, 0xF, true); x += __int_as_float(t); // row_shr:8
    t = __builtin_amdgcn_update_dpp(0, __float_as_int(x), 0x142, 0xF, 0xF, true); x += __int_as_float(t); // row_bcast:15
    t = __builtin_amdgcn_update_dpp(0, __float_as_int(x), 0x143, 0xF, 0xF, true); x += __int_as_float(t); // row_bcast:31
    return x; // lane 63 holds the full 64-lane sum
}

// Tree-shaped sum of exp over 16 values (depth 4).
__device__ __forceinline__ float exp16_sum(const float4& v0, const float4& v1,
                                           const float4& v2, const float4& v3) {
    float a0 = __expf(v0.x) + __expf(v0.y), a1 = __expf(v0.z) + __expf(v0.w);
    float a2 = __expf(v1.x) + __expf(v1.y), a3 = __expf(v1.z) + __expf(v1.w);
    float a4 = __expf(v2.x) + __expf(v2.y), a5 = __expf(v2.z) + __expf(v2.w);
    float a6 = __expf(v3.x) + __expf(v3.y), a7 = __expf(v3.z) + __expf(v3.w);
    float b0 = a0 + a1, b1 = a2 + a3, b2 = a4 + a5, b3 = a6 + a7;
    return (b0 + b1) + (b2 + b3);
}

// One wave per row, 1 row per stage, 4 register phases, prefetch 3 stages
// ahead (3 batches/wave in flight -> finer vmcnt waits, more MLP than R4's
// wait-all 8KB stages). 64 rows/block, 4 waves, 16 consecutive rows/wave,
// 16 fully-unrolled stages. Per-bin (count, loss-sum) in LDS; block flushes
// either to per-block partial slots (use_part=1, no memset needed: full
// overwrite each call) or via global atomics (fallback, needs zeroed ws).
__global__ __launch_bounds__(256) void ghmc_pass1(
    const float* __restrict__ pred,
    const int*   __restrict__ target,
    int*   __restrict__ pcnt,
    float* __restrict__ psum,
    int nrows, int use_part)
{
    __shared__ int   s_cnt[BINS];
    __shared__ float s_sum[BINS];
    if (threadIdx.x < BINS) { s_cnt[threadIdx.x] = 0; s_sum[threadIdx.x] = 0.0f; }
    __syncthreads();

    const int lane = threadIdx.x & 63;
    const int wv   = threadIdx.x >> 6;
    const int base = blockIdx.x * 64 + wv * 16;   // wave owns rows base..base+15
    const float NEG = -INFINITY;

    // Preload all 16 targets (wave-uniform addresses -> scalar loads).
    int tgt[16];
    #pragma unroll
    for (int k = 0; k < 16; ++k) tgt[k] = target[min(base + k, nrows - 1)];

    float4 C0[4], C1[4], C2[4], C3[4];
    float  pt[4];

#define LOADK(kk, pp) do {                                                    \
    const int r_ = min(base + (kk), nrows - 1);                               \
    const float4* rp_ = (const float4*)(pred + (size_t)r_ * NCLS);            \
    C0[pp] = rp_[lane]; C1[pp] = rp_[lane + 64]; C2[pp] = rp_[lane + 128];    \
    if (lane < 58) C3[pp] = rp_[lane + 192];                                  \
    else           C3[pp] = make_float4(NEG, NEG, NEG, NEG);                  \
    pt[pp] = pred[(size_t)r_ * NCLS + tgt[kk]];                               \
} while (0)

    LOADK(0, 0);  LOADK(1, 1);  LOADK(2, 2);   // prologue: 3 batches in flight

    #pragma unroll
    for (int k = 0; k < 16; ++k) {
        const int p = k & 3;
        if (k < 13) LOADK(k + 3, (k + 3) & 3);   // keep 3 batches outstanding

        float s = exp16_sum(C0[p], C1[p], C2[p], C3[p]);
        s = dpp_reduce_add_lane63(s);

        if (lane == 63 && base + k < nrows) {
            const float loss = -pt[p] + __logf(s + EPSV);
            const float g = 1.0f - __expf(pt[p]) / s;
            int b = (int)floorf(g * 10.0f);
            b = min(max(b, 0), BINS - 1);
            atomicAdd(&s_cnt[b], 1);
            atomicAdd(&s_sum[b], loss);
        }
    }
#undef LOADK

    __syncthreads();
    if (threadIdx.x < BINS) {
        if (use_part) {   // per-block slot: full overwrite, deterministic
            pcnt[blockIdx.x * BINS + threadIdx.x] = s_cnt[threadIdx.x];
            psum[blockIdx.x * BINS + threadIdx.x] = s_sum[threadIdx.x];
        } else if (s_cnt[threadIdx.x] > 0) {
            atomicAdd(&pcnt[threadIdx.x], s_cnt[threadIdx.x]);
            atomicAdd(&psum[threadIdx.x], s_sum[threadIdx.x]);
        }
    }
}

// Pass 2: reduce nblk x 10 partials, then combine the 10 bins.
// out = sum_b (loss_sum[b] / counts[b]) / n_nonempty
__global__ __launch_bounds__(256) void ghmc_pass2(
    const int* __restrict__ pcnt,
    const float* __restrict__ psum,
    float* __restrict__ out, int nblk)
{
    const int lane = threadIdx.x & 63;
    const int wv   = threadIdx.x >> 6;

    float cnt[BINS], sum[BINS];
    #pragma unroll
    for (int b = 0; b < BINS; ++b) { cnt[b] = 0.0f; sum[b] = 0.0f; }

    for (int blk = threadIdx.x; blk < nblk; blk += 256) {
        #pragma unroll
        for (int b = 0; b < BINS; ++b) {
            cnt[b] += (float)pcnt[blk * BINS + b];   // counts <= 65536: exact in f32
            sum[b] += psum[blk * BINS + b];
        }
    }

    __shared__ float sc[4][BINS], ss[4][BINS];
    #pragma unroll
    for (int b = 0; b < BINS; ++b) {
        const float c = dpp_reduce_add_lane63(cnt[b]);
        const float s = dpp_reduce_add_lane63(sum[b]);
        if (lane == 63) { sc[wv][b] = c; ss[wv][b] = s; }
    }
    __syncthreads();

    if (threadIdx.x == 0) {
        int n = 0;
        float acc = 0.0f;
        for (int b = 0; b < BINS; ++b) {
            const float c = sc[0][b] + sc[1][b] + sc[2][b] + sc[3][b];
            const float s = ss[0][b] + ss[1][b] + ss[2][b] + ss[3][b];
            if (c > 0.0f) { n += 1; acc += s / c; }
        }
        out[0] = acc / (float)max(n, 1);
    }
}

extern "C" void kernel_launch(void* const* d_in, const int* in_sizes, int n_in,
                              void* d_out, int out_size, void* d_ws, size_t ws_size,
                              hipStream_t stream)
{
    const float* pred   = (const float*)d_in[0];
    const int*   target = (const int*)d_in[1];
    const int nrows  = in_sizes[1];            // 65536
    const int blocks = (nrows + 63) / 64;      // 1024

    const size_t cnt_bytes = (size_t)blocks * BINS * sizeof(int);   // 40 KB
    const size_t need = 2 * ((cnt_bytes + 63) & ~(size_t)63);

    if (ws_size >= need) {
        // Per-block partial slots: no memset, no global atomics.
        int*   pcnt = (int*)d_ws;
        float* psum = (float*)((char*)d_ws + ((cnt_bytes + 63) & ~(size_t)63));
        ghmc_pass1<<<blocks, 256, 0, stream>>>(pred, target, pcnt, psum, nrows, 1);
        ghmc_pass2<<<1, 256, 0, stream>>>(pcnt, psum, (float*)d_out, blocks);
    } else {
        // Fallback: zeroed 10-bin arrays + global atomics.
        int*   pcnt = (int*)d_ws;
        float* psum = (float*)((char*)d_ws + 64);
        hipMemsetAsync(d_ws, 0, 128, stream);
        ghmc_pass1<<<blocks, 256, 0, stream>>>(pred, target, pcnt, psum, nrows, 0);
        ghmc_pass2<<<1, 256, 0, stream>>>(pcnt, psum, (float*)d_out, 1);
    }
}